// Round 1
// baseline (884.052 us; speedup 1.0000x reference)
//
#include <hip/hip_runtime.h>
#include <cstdint>
#include <cstddef>

#define D 64

__device__ __forceinline__ uint32_t f2bf_rne(float x) {
  uint32_t u = __float_as_uint(x);
  return (u + 0x7FFFu + ((u >> 16) & 1u)) >> 16;
}

// -----------------------------------------------------------------------------
// Kernel 1: Yt[m][o] = bf16( sum_d W[o][d] * V[d][m] )
// grid = M/64 blocks, 64 threads. 8x8 register tile per thread (64x64 C tile).
// -----------------------------------------------------------------------------
__global__ __launch_bounds__(64) void k1_precompute(
    const float* __restrict__ V,   // [D][M] row-major
    const float* __restrict__ W,   // [D][D] row-major, W[o][d]
    uint16_t* __restrict__ Yt,     // [M][D] bf16
    int M)
{
  __shared__ float sW[D * 66];   // sW[d][o]  (W transposed), pitch 66
  __shared__ float sV[D * 66];   // sV[d][m_local], pitch 66

  const int t = threadIdx.x;       // 0..63
  const int mbase = blockIdx.x * D;

  // ---- W -> LDS transposed. thread t owns row o=t: stores hit bank (t%32) -> 2-way, free.
  {
    const float4* wrow = (const float4*)(W + t * D);
#pragma unroll
    for (int c = 0; c < 16; ++c) {
      float4 w4 = wrow[c];
      sW[(c * 4 + 0) * 66 + t] = w4.x;
      sW[(c * 4 + 1) * 66 + t] = w4.y;
      sW[(c * 4 + 2) * 66 + t] = w4.z;
      sW[(c * 4 + 3) * 66 + t] = w4.w;
    }
  }
  // ---- V tile -> LDS. 4 rows x 16 lanes per iter, coalesced 256B/row.
  {
    const int idx16 = t & 15;      // float4 column within row
    const int dg = t >> 4;         // 0..3
#pragma unroll
    for (int c = 0; c < 16; ++c) {
      const int d = dg + 4 * c;    // d = dg+4c => store banks 2(dg)+4(idx16): 2-way, free
      float4 v4 = *(const float4*)(V + (size_t)d * M + mbase + idx16 * 4);
      sV[d * 66 + idx16 * 4 + 0] = v4.x;
      sV[d * 66 + idx16 * 4 + 1] = v4.y;
      sV[d * 66 + idx16 * 4 + 2] = v4.z;
      sV[d * 66 + idx16 * 4 + 3] = v4.w;
    }
  }
  __syncthreads();

  const int o0 = (t & 7) * 8;
  const int m0 = (t >> 3) * 8;
  float acc[8][8];
#pragma unroll
  for (int i = 0; i < 8; ++i)
#pragma unroll
    for (int j = 0; j < 8; ++j) acc[i][j] = 0.0f;

  for (int d = 0; d < D; ++d) {
    float w[8], v[8];
#pragma unroll
    for (int i = 0; i < 8; i += 2) {    // float2 (ds_read_b64), 8B-aligned: pitch 66 even, o0/m0 even
      float2 a = *(const float2*)(&sW[d * 66 + o0 + i]);
      w[i] = a.x; w[i + 1] = a.y;
      float2 b = *(const float2*)(&sV[d * 66 + m0 + i]);
      v[i] = b.x; v[i + 1] = b.y;
    }
#pragma unroll
    for (int i = 0; i < 8; ++i)
#pragma unroll
      for (int j = 0; j < 8; ++j)
        acc[i][j] = fmaf(w[i], v[j], acc[i][j]);
  }

  // ---- epilogue: pack 8 bf16 per m-row, uint4 store (128B/row coalesced across lanes)
#pragma unroll
  for (int j = 0; j < 8; ++j) {
    uint32_t h0 = f2bf_rne(acc[0][j]) | (f2bf_rne(acc[1][j]) << 16);
    uint32_t h1 = f2bf_rne(acc[2][j]) | (f2bf_rne(acc[3][j]) << 16);
    uint32_t h2 = f2bf_rne(acc[4][j]) | (f2bf_rne(acc[5][j]) << 16);
    uint32_t h3 = f2bf_rne(acc[6][j]) | (f2bf_rne(acc[7][j]) << 16);
    uint4 pk; pk.x = h0; pk.y = h1; pk.z = h2; pk.w = h3;
    *(uint4*)(Yt + (size_t)(mbase + m0 + j) * D + o0) = pk;
  }
}

// -----------------------------------------------------------------------------
// Kernel 2: out[o][k] = fp32( Yt[ in_idx[out_idx[k]] ][o] )
// grid = N_OUT/64 blocks, 256 threads. 64x64 transpose tile through LDS.
// -----------------------------------------------------------------------------
__global__ __launch_bounds__(256) void k2_gather(
    const uint16_t* __restrict__ Yt,   // [M][D] bf16
    const int* __restrict__ in_idx,
    const int* __restrict__ out_idx,
    float* __restrict__ out,           // [D][N_OUT]
    int N_OUT)
{
  __shared__ float sT[D * 65];   // sT[k][o], pitch 65
  __shared__ int sIdx[D];

  const int t = threadIdx.x;
  const int kbase = blockIdx.x * D;

  if (t < D) {
    sIdx[t] = in_idx[out_idx[kbase + t]];
  }
  __syncthreads();

  // phase 1: gather 64 rows x 128B (uint4 = 8 bf16 per lane), cvt -> fp32 LDS
  {
    const int r5 = t & 31;
    const int bhi = (t >> 5) & 1;
    const int c0 = t >> 6;                 // wave id 0..3
    const int row = r5 + 32 * bhi;
#pragma unroll
    for (int j = 0; j < 2; ++j) {
      const int chunk = c0 + 4 * j;        // 0..7 (16B of the 128B row)
      const uint16_t* src = Yt + (size_t)sIdx[row] * D + chunk * 8;
      uint4 p = *(const uint4*)src;
      float* dstl = &sT[row * 65 + chunk * 8];  // bank = r5 + const -> 2-way, free
      dstl[0] = __uint_as_float(p.x << 16);
      dstl[1] = __uint_as_float(p.x & 0xFFFF0000u);
      dstl[2] = __uint_as_float(p.y << 16);
      dstl[3] = __uint_as_float(p.y & 0xFFFF0000u);
      dstl[4] = __uint_as_float(p.z << 16);
      dstl[5] = __uint_as_float(p.z & 0xFFFF0000u);
      dstl[6] = __uint_as_float(p.w << 16);
      dstl[7] = __uint_as_float(p.w & 0xFFFF0000u);
    }
  }
  __syncthreads();

  // phase 2: transpose out of LDS; each thread writes 64B contiguous along k
  {
    const int o = t >> 2;                  // 0..63
    const int ks = (t & 3) * 16;           // 0,16,32,48
    float* dst = out + (size_t)o * N_OUT + kbase + ks;
#pragma unroll
    for (int j = 0; j < 4; ++j) {
      float4 v;
      v.x = sT[(ks + 4 * j + 0) * 65 + o]; // bank = (ks+o+c)%32 -> 2-way, free
      v.y = sT[(ks + 4 * j + 1) * 65 + o];
      v.z = sT[(ks + 4 * j + 2) * 65 + o];
      v.w = sT[(ks + 4 * j + 3) * 65 + o];
      *(float4*)(dst + 4 * j) = v;
    }
  }
}

// -----------------------------------------------------------------------------
// Fallback (only if ws_size < 128MB): slow but correct direct compute.
// -----------------------------------------------------------------------------
__global__ __launch_bounds__(64) void k_fallback(
    const float* __restrict__ V, const float* __restrict__ W,
    const int* __restrict__ in_idx, const int* __restrict__ out_idx,
    float* __restrict__ out, int M, int N_OUT)
{
  const int k = blockIdx.x;
  const int o = threadIdx.x;
  const int g = in_idx[out_idx[k]];
  float s = 0.0f;
  for (int d = 0; d < D; ++d)
    s = fmaf(W[o * D + d], V[(size_t)d * M + g], s);
  out[(size_t)o * N_OUT + k] = s;
}

extern "C" void kernel_launch(void* const* d_in, const int* in_sizes, int n_in,
                              void* d_out, int out_size, void* d_ws, size_t ws_size,
                              hipStream_t stream) {
  const float* V       = (const float*)d_in[0];
  const float* W       = (const float*)d_in[1];
  const int*   in_idx  = (const int*)d_in[2];
  const int*   out_idx = (const int*)d_in[3];
  float* out = (float*)d_out;

  const int M     = in_sizes[0] / D;   // 1,000,000
  const int N_OUT = in_sizes[3];       // 2,000,000

  const size_t yt_bytes = (size_t)M * D * sizeof(uint16_t);  // 128 MB
  if (ws_size >= yt_bytes && (M % D) == 0 && (N_OUT % D) == 0) {
    uint16_t* Yt = (uint16_t*)d_ws;
    k1_precompute<<<M / D, 64, 0, stream>>>(V, W, Yt, M);
    k2_gather<<<N_OUT / D, 256, 0, stream>>>(Yt, in_idx, out_idx, out, N_OUT);
  } else {
    k_fallback<<<N_OUT, 64, 0, stream>>>(V, W, in_idx, out_idx, out, M, N_OUT);
  }
}